// Round 5
// baseline (356.944 us; speedup 1.0000x reference)
//
#include <hip/hip_runtime.h>

typedef unsigned short u16;
typedef unsigned int u32;
using bf16x8 = __attribute__((ext_vector_type(8))) short;
using f32x4  = __attribute__((ext_vector_type(4))) float;

__device__ __forceinline__ u16 f2bf(float f) {
  u32 u = __float_as_uint(f);
  return (u16)((u + 0x7FFFu + ((u >> 16) & 1u)) >> 16);
}
__device__ __forceinline__ float bf2f(u16 h) {
  return __uint_as_float(((u32)h) << 16);
}

// ---------------- conv 3x3, 3->64, SAME, ReLU; out fmap[y][x][c] bf16 --------
__global__ __launch_bounds__(256) void conv3x3_relu_k(
    const float* __restrict__ img, const float* __restrict__ w,
    const float* __restrict__ bias, u16* __restrict__ fmap) {
  int p = blockIdx.x * 256 + threadIdx.x;  // 0..262143
  int y = p >> 9, x = p & 511;
  float v[27];
#pragma unroll
  for (int ci = 0; ci < 3; ++ci)
#pragma unroll
    for (int ky = 0; ky < 3; ++ky)
#pragma unroll
      for (int kx = 0; kx < 3; ++kx) {
        int yy = y + ky - 1, xx = x + kx - 1;
        bool ok = (yy >= 0) && (yy < 512) && (xx >= 0) && (xx < 512);
        v[(ci * 3 + ky) * 3 + kx] = ok ? img[ci * 262144 + yy * 512 + xx] : 0.f;
      }
  float acc[64];
#pragma unroll
  for (int co = 0; co < 64; ++co) {
    float s = bias[co];
#pragma unroll
    for (int q = 0; q < 27; ++q) s = fmaf(w[co * 27 + q], v[q], s);
    acc[co] = fmaxf(s, 0.f);
  }
  uint4* dst = (uint4*)((u32*)fmap + (size_t)p * 32);
#pragma unroll
  for (int q = 0; q < 8; ++q) {
    uint4 d;
    d.x = (u32)f2bf(acc[8 * q + 0]) | ((u32)f2bf(acc[8 * q + 1]) << 16);
    d.y = (u32)f2bf(acc[8 * q + 2]) | ((u32)f2bf(acc[8 * q + 3]) << 16);
    d.z = (u32)f2bf(acc[8 * q + 4]) | ((u32)f2bf(acc[8 * q + 5]) << 16);
    d.w = (u32)f2bf(acc[8 * q + 6]) | ((u32)f2bf(acc[8 * q + 7]) << 16);
    dst[q] = d;
  }
}

// ---------------- RoI max pool: block per roi; feat[n][c*49+py*7+px] bf16 ----
__global__ __launch_bounds__(256) void roipool_k(
    const u16* __restrict__ fmap, const int* __restrict__ regions,
    u16* __restrict__ feat) {
  int n = blockIdx.x, t = threadIdx.x;
  uint4* fdst = (uint4*)(feat + (size_t)n * 3136);  // 392 uint4 per row
  if (n >= 2000) {  // zero pad rows so GEMM needs no edge masking
    uint4 z; z.x = z.y = z.z = z.w = 0u;
    fdst[t % 392] = z;
    int t2 = t + 256; if (t2 < 392) fdst[t2] = z;
    if (t < 392) fdst[t] = z;
    return;
  }
  int r0 = regions[2 * n], c0 = regions[2 * n + 1];
  __shared__ uint2 rows_u2[1792];  // 4 rows x 28 x 64c bf16 = 14336 B
  __shared__ uint4 frow4[392];     // 3136 bf16 = 6272 B
  u16* rows = (u16*)rows_u2;
  u16* frow = (u16*)frow4;
  for (int py = 0; py < 7; ++py) {
#pragma unroll
    for (int q = 0; q < 7; ++q) {
      int cid = t + q * 256;           // 0..1791, 8B chunks
      int i = cid / 448, rem = cid % 448;
      int xo = rem >> 4, c4 = (rem & 15) << 2;
      int yy = r0 + py * 4 + i, xx = c0 + xo;
      rows_u2[cid] = *(const uint2*)(fmap + (((size_t)(yy * 512 + xx)) << 6) + c4);
    }
    __syncthreads();
#pragma unroll
    for (int h = 0; h < 2; ++h) {
      int o = t + h * 256;
      if (o < 448) {
        int c = o & 63, px = o >> 6;
        float best = -3.0e38f;
#pragma unroll
        for (int i = 0; i < 4; ++i)
#pragma unroll
          for (int j = 0; j < 4; ++j)
            best = fmaxf(best, bf2f(rows[(i * 28 + px * 4 + j) * 64 + c]));
        frow[c * 49 + py * 7 + px] = f2bf(best);
      }
    }
    __syncthreads();
  }
  if (t < 392) fdst[t] = frow4[t];
  int t2 = t + 256;
  if (t2 < 392) fdst[t2] = frow4[t2];
}

// ---------------- fp32 -> bf16 conversion (vectorized) -----------------------
__global__ __launch_bounds__(256) void f2bf_k(const float* __restrict__ in,
                                              u16* __restrict__ out, int n4) {
  int idx = blockIdx.x * 256 + threadIdx.x;
  int stride = gridDim.x * 256;
  for (int i = idx; i < n4; i += stride) {
    float4 v = ((const float4*)in)[i];
    uint2 o;
    o.x = (u32)f2bf(v.x) | ((u32)f2bf(v.y) << 16);
    o.y = (u32)f2bf(v.z) | ((u32)f2bf(v.w) << 16);
    ((uint2*)out)[i] = o;
  }
}

// ---------------- 8-wave 256x256 split-K bf16 GEMM (B^T), partials to fp32 P.
// m201-style chunk pipeline: K-tile (BK=64) = 4 chunks of 16KB
// {A-kh0, B-kh0, A-kh1, B-kh1}; 4 phases/tile, 1 chunk (2 G2L) issued/phase,
// counted vmcnt(6) twice per tile (3 chunks always in flight), never 0 except
// the last two tile boundaries. 2 LDS buffers (128 KB).
// Per-wave output 128x64 (8 waves = 2M x 4N). T2 swizzle: 64 B rows, phys
// 16B-slot = s ^ ((r>>1)&3)  (bijective, 2-way max on frag reads).
// grid = 256 blocks: 8 mb x 16 nb x 2 sk (XCD-aware remap).
__global__ __launch_bounds__(512, 2) void gemm256_splitk_k(
    const u16* __restrict__ A, const u16* __restrict__ B,
    float* __restrict__ P, int N, int K, int NT0, int NT) {
  __shared__ uint4 lds4[8192];  // 131072 B: 2 x {A0|B0|A1|B1} x 16 KB
  char* ldsb = (char*)lds4;
  const int t = threadIdx.x;
  const int lane = t & 63, wv = t >> 6;
  const int wm = wv >> 2, wn = wv & 3;

  int bid = blockIdx.x;                      // grid must be exactly 256
  int swz = ((bid & 7) << 5) | (bid >> 3);   // XCD-contiguous remap (bijective)
  const int sk = swz >> 7;
  const int mb = swz & 7, nb = (swz >> 3) & 15;
  const int m0 = mb * 256, n0 = nb * 256;
  const int t0 = sk ? NT0 : 0;
  const int NTb = (sk ? NT : NT0) - t0;

  const u16* __restrict__ Ab = A + (size_t)m0 * K;
  const u16* __restrict__ Bb = B + (size_t)n0 * K;

  // staging: chunk = 256 rows x 64 B; sweep = 128 rows (8 KB, 2/G2L chunk).
  // thread t -> row t>>2, dest slot t&3 (linear), source slot pre-swizzled.
  const int srow = t >> 2;
  const int sslot = (t & 3) ^ ((srow >> 1) & 3);
  const u16* sA = Ab + (size_t)srow * K + sslot * 8;
  const u16* sB = Bb + (size_t)srow * K + sslot * 8;
  const size_t K128 = (size_t)128 * K;
  const int dof = t * 16;

#define G2L(src, ldst)                                                        \
  __builtin_amdgcn_global_load_lds(                                          \
      (const __attribute__((address_space(1))) void*)(src),                  \
      (__attribute__((address_space(3))) void*)(ldst), 16, 0, 0)
#define LOFF(r, s) (((r) << 6) + ((((s) ^ (((r) >> 1) & 3))) << 4))

  const int row16 = lane & 15, sl = lane >> 4;
  f32x4 acc[8][4] = {};
  bf16x8 afr[4], bfr[4];

  // ---- prologue: tile0 all 4 chunks -> buf0; tile1 chunks A0,B0 -> buf1
  {
    char* b0 = ldsb;
    const size_t ko = (size_t)t0 * 64;
    G2L(sA + ko, b0 + dof);                 G2L(sA + K128 + ko, b0 + 8192 + dof);
    G2L(sB + ko, b0 + 16384 + dof);         G2L(sB + K128 + ko, b0 + 24576 + dof);
    G2L(sA + ko + 32, b0 + 32768 + dof);    G2L(sA + K128 + ko + 32, b0 + 40960 + dof);
    G2L(sB + ko + 32, b0 + 49152 + dof);    G2L(sB + K128 + ko + 32, b0 + 57344 + dof);
    if (NTb > 1) {
      char* b1 = ldsb + 65536;
      const size_t k1 = ko + 64;
      G2L(sA + k1, b1 + dof);               G2L(sA + K128 + k1, b1 + 8192 + dof);
      G2L(sB + k1, b1 + 16384 + dof);       G2L(sB + K128 + k1, b1 + 24576 + dof);
      asm volatile("s_waitcnt vmcnt(6)" ::: "memory");
    } else {
      asm volatile("s_waitcnt vmcnt(0)" ::: "memory");
    }
  }
  __builtin_amdgcn_s_barrier();

  for (int tt = 0; tt < NTb; ++tt) {
    char* cbuf = ldsb + (tt & 1) * 65536;
    char* nbuf = ldsb + ((tt & 1) ^ 1) * 65536;
    char* Ac0 = cbuf;           char* Bc0 = cbuf + 16384;
    char* Ac1 = cbuf + 32768;   char* Bc1 = cbuf + 49152;
    const size_t kbase = (size_t)(t0 + tt) * 64;
    const bool pf1 = (tt + 1) < NTb;
    const bool pf2 = (tt + 2) < NTb;

    // ===== phase 0: read B-kh0 + A-kh0[i0..3]; issue (t+1, A-kh1)
#pragma unroll
    for (int j = 0; j < 4; ++j)
      bfr[j] = *(const bf16x8*)(Bc0 + LOFF(wn * 64 + j * 16 + row16, sl));
#pragma unroll
    for (int ii = 0; ii < 4; ++ii)
      afr[ii] = *(const bf16x8*)(Ac0 + LOFF(wm * 128 + ii * 16 + row16, sl));
    if (pf1) {
      const size_t ko = kbase + 64 + 32;
      G2L(sA + ko, nbuf + 32768 + dof);  G2L(sA + K128 + ko, nbuf + 40960 + dof);
    }
    __builtin_amdgcn_s_barrier();
    asm volatile("s_waitcnt lgkmcnt(0)" ::: "memory");
    __builtin_amdgcn_sched_barrier(0);
    __builtin_amdgcn_s_setprio(1);
#pragma unroll
    for (int ii = 0; ii < 4; ++ii)
#pragma unroll
      for (int j = 0; j < 4; ++j)
        acc[ii][j] = __builtin_amdgcn_mfma_f32_16x16x32_bf16(afr[ii], bfr[j], acc[ii][j], 0, 0, 0);
    __builtin_amdgcn_s_setprio(0);
    __builtin_amdgcn_s_barrier();

    // ===== phase 1: read A-kh0[i4..7]; issue (t+1, B-kh1); vmcnt
#pragma unroll
    for (int ii = 0; ii < 4; ++ii)
      afr[ii] = *(const bf16x8*)(Ac0 + LOFF(wm * 128 + (ii + 4) * 16 + row16, sl));
    if (pf1) {
      const size_t ko = kbase + 64 + 32;
      G2L(sB + ko, nbuf + 49152 + dof);  G2L(sB + K128 + ko, nbuf + 57344 + dof);
    }
    __builtin_amdgcn_s_barrier();
    asm volatile("s_waitcnt lgkmcnt(0)" ::: "memory");
    __builtin_amdgcn_sched_barrier(0);
    __builtin_amdgcn_s_setprio(1);
#pragma unroll
    for (int ii = 0; ii < 4; ++ii)
#pragma unroll
      for (int j = 0; j < 4; ++j)
        acc[ii + 4][j] = __builtin_amdgcn_mfma_f32_16x16x32_bf16(afr[ii], bfr[j], acc[ii + 4][j], 0, 0, 0);
    __builtin_amdgcn_s_setprio(0);
    if (pf1) asm volatile("s_waitcnt vmcnt(6)" ::: "memory");
    else     asm volatile("s_waitcnt vmcnt(0)" ::: "memory");
    __builtin_amdgcn_s_barrier();

    // ===== phase 2: read B-kh1 + A-kh1[i0..3]; issue (t+2, A-kh0) into cbuf
#pragma unroll
    for (int j = 0; j < 4; ++j)
      bfr[j] = *(const bf16x8*)(Bc1 + LOFF(wn * 64 + j * 16 + row16, sl));
#pragma unroll
    for (int ii = 0; ii < 4; ++ii)
      afr[ii] = *(const bf16x8*)(Ac1 + LOFF(wm * 128 + ii * 16 + row16, sl));
    if (pf2) {
      const size_t ko = kbase + 128;
      G2L(sA + ko, cbuf + dof);  G2L(sA + K128 + ko, cbuf + 8192 + dof);
    }
    __builtin_amdgcn_s_barrier();
    asm volatile("s_waitcnt lgkmcnt(0)" ::: "memory");
    __builtin_amdgcn_sched_barrier(0);
    __builtin_amdgcn_s_setprio(1);
#pragma unroll
    for (int ii = 0; ii < 4; ++ii)
#pragma unroll
      for (int j = 0; j < 4; ++j)
        acc[ii][j] = __builtin_amdgcn_mfma_f32_16x16x32_bf16(afr[ii], bfr[j], acc[ii][j], 0, 0, 0);
    __builtin_amdgcn_s_setprio(0);
    __builtin_amdgcn_s_barrier();

    // ===== phase 3: read A-kh1[i4..7]; issue (t+2, B-kh0) into cbuf; vmcnt
#pragma unroll
    for (int ii = 0; ii < 4; ++ii)
      afr[ii] = *(const bf16x8*)(Ac1 + LOFF(wm * 128 + (ii + 4) * 16 + row16, sl));
    if (pf2) {
      const size_t ko = kbase + 128;
      G2L(sB + ko, cbuf + 16384 + dof);  G2L(sB + K128 + ko, cbuf + 24576 + dof);
    }
    __builtin_amdgcn_s_barrier();
    asm volatile("s_waitcnt lgkmcnt(0)" ::: "memory");
    __builtin_amdgcn_sched_barrier(0);
    __builtin_amdgcn_s_setprio(1);
#pragma unroll
    for (int ii = 0; ii < 4; ++ii)
#pragma unroll
      for (int j = 0; j < 4; ++j)
        acc[ii + 4][j] = __builtin_amdgcn_mfma_f32_16x16x32_bf16(afr[ii], bfr[j], acc[ii + 4][j], 0, 0, 0);
    __builtin_amdgcn_s_setprio(0);
    if (pf2) asm volatile("s_waitcnt vmcnt(6)" ::: "memory");
    else     asm volatile("s_waitcnt vmcnt(0)" ::: "memory");
    __builtin_amdgcn_s_barrier();
  }
#undef G2L
#undef LOFF

  // ---- epilogue: atomic-add fp32 partials (2 contributions/elem -> exact)
#pragma unroll
  for (int i = 0; i < 8; ++i)
#pragma unroll
    for (int j = 0; j < 4; ++j) {
      const int cg = n0 + wn * 64 + j * 16 + row16;
#pragma unroll
      for (int r = 0; r < 4; ++r) {
        const int rg = m0 + wm * 128 + i * 16 + sl * 4 + r;
        atomicAdd(&P[(size_t)rg * N + cg], acc[i][j][r]);
      }
    }
}

// ---------------- finalize: H = bf16(relu(P + bias[col])), row-major 2048x4096
__global__ __launch_bounds__(256) void finalize_k(
    const float* __restrict__ P, const float* __restrict__ bias,
    u16* __restrict__ H, int total8) {
  int i = blockIdx.x * 256 + threadIdx.x;
  int stride = gridDim.x * 256;
  for (; i < total8; i += stride) {
    const float4* p4 = (const float4*)(P + (size_t)i * 8);
    float4 v0 = p4[0], v1 = p4[1];
    int col = (i * 8) & 4095;
    float4 b0 = *(const float4*)(bias + col);
    float4 b1 = *(const float4*)(bias + col + 4);
    float r0 = fmaxf(v0.x + b0.x, 0.f), r1 = fmaxf(v0.y + b0.y, 0.f);
    float r2 = fmaxf(v0.z + b0.z, 0.f), r3 = fmaxf(v0.w + b0.w, 0.f);
    float r4 = fmaxf(v1.x + b1.x, 0.f), r5 = fmaxf(v1.y + b1.y, 0.f);
    float r6 = fmaxf(v1.z + b1.z, 0.f), r7 = fmaxf(v1.w + b1.w, 0.f);
    uint4 o;
    o.x = (u32)f2bf(r0) | ((u32)f2bf(r1) << 16);
    o.y = (u32)f2bf(r2) | ((u32)f2bf(r3) << 16);
    o.z = (u32)f2bf(r4) | ((u32)f2bf(r5) << 16);
    o.w = (u32)f2bf(r6) | ((u32)f2bf(r7) << 16);
    ((uint4*)H)[i] = o;
  }
}

// ---------------- cls/bbox heads: block per roi, 10 dots of K=4096 -----------
__global__ __launch_bounds__(256) void heads_k(
    const u16* __restrict__ h2, const float* __restrict__ cw,
    const float* __restrict__ cb, const float* __restrict__ bw,
    const float* __restrict__ bb, float* __restrict__ out) {
  int m = blockIdx.x, t = threadIdx.x;
  const u16* hrow = h2 + (size_t)m * 4096;
  float p[10];
#pragma unroll
  for (int j = 0; j < 10; ++j) p[j] = 0.f;
  for (int k = t; k < 4096; k += 256) {
    float v = bf2f(hrow[k]);
    p[0] = fmaf(v, cw[k], p[0]);
    p[1] = fmaf(v, cw[4096 + k], p[1]);
#pragma unroll
    for (int j = 0; j < 8; ++j) p[2 + j] = fmaf(v, bw[j * 4096 + k], p[2 + j]);
  }
#pragma unroll
  for (int j = 0; j < 10; ++j)
#pragma unroll
    for (int off = 32; off > 0; off >>= 1) p[j] += __shfl_down(p[j], off);
  __shared__ float red[4][10];
  int lane = t & 63, wv = t >> 6;
  if (lane == 0) {
#pragma unroll
    for (int j = 0; j < 10; ++j) red[wv][j] = p[j];
  }
  __syncthreads();
  if (t < 10) {
    float s = red[0][t] + red[1][t] + red[2][t] + red[3][t];
    s += (t < 2) ? cb[t] : bb[t - 2];
    if (t < 2) out[m * 2 + t] = s;
    else out[4000 + m * 8 + (t - 2)] = s;
  }
}

extern "C" void kernel_launch(void* const* d_in, const int* in_sizes, int n_in,
                              void* d_out, int out_size, void* d_ws, size_t ws_size,
                              hipStream_t stream) {
  const float* img    = (const float*)d_in[0];
  const int*   regions= (const int*)d_in[1];
  const float* conv_w = (const float*)d_in[2];
  const float* conv_b = (const float*)d_in[3];
  const float* fc1_w  = (const float*)d_in[4];
  const float* fc1_b  = (const float*)d_in[5];
  const float* fc2_w  = (const float*)d_in[6];
  const float* fc2_b  = (const float*)d_in[7];
  const float* cls_w  = (const float*)d_in[8];
  const float* cls_b  = (const float*)d_in[9];
  const float* bbox_w = (const float*)d_in[10];
  const float* bbox_b = (const float*)d_in[11];
  float* out = (float*)d_out;

  char* ws = (char*)d_ws;
  // layout (bytes), total 105,644,032:
  //   [0, 33554432)          fmap [512][512][64] bf16; later h1=[0,16M), h2=[16M,32M)
  //   [33554432, 46399488)   feat [2048][3136] bf16; later w2b [4096][4096] bf16
  //                          occupies [33554432, 67108864)
  //   [46399488, 72089600)   w1b  [4096][3136] bf16 (dead after fc1)
  //   [72089600, 105644032)  P1   [2048][4096] fp32 partials (33.55 MB)
  u16* fmap = (u16*)(ws);
  u16* h1   = (u16*)(ws);
  u16* h2   = (u16*)(ws + 16777216);
  u16* feat = (u16*)(ws + 33554432);
  u16* w1b  = (u16*)(ws + 46399488);
  u16* w2b  = (u16*)(ws + 33554432);   // reuses feat+w1b region after fc1
  float* P1 = (float*)(ws + 72089600);

  conv3x3_relu_k<<<1024, 256, 0, stream>>>(img, conv_w, conv_b, fmap);
  roipool_k<<<2048, 256, 0, stream>>>(fmap, regions, feat);
  f2bf_k<<<2048, 256, 0, stream>>>(fc1_w, w1b, 4096 * 3136 / 4);
  hipMemsetAsync(P1, 0, 33554432, stream);
  gemm256_splitk_k<<<256, 512, 0, stream>>>(feat, w1b, P1, 4096, 3136, 25, 49);
  finalize_k<<<2048, 256, 0, stream>>>(P1, fc1_b, h1, 1048576);
  f2bf_k<<<2048, 256, 0, stream>>>(fc2_w, w2b, 4096 * 4096 / 4);
  hipMemsetAsync(P1, 0, 33554432, stream);
  gemm256_splitk_k<<<256, 512, 0, stream>>>(h1, w2b, P1, 4096, 4096, 32, 64);
  finalize_k<<<2048, 256, 0, stream>>>(P1, fc2_b, h2, 1048576);
  heads_k<<<2000, 256, 0, stream>>>(h2, cls_w, cls_b, bbox_w, bbox_b, out);
}

// Round 6
// 238.958 us; speedup vs baseline: 1.4938x; 1.4938x over previous
//
#include <hip/hip_runtime.h>

typedef unsigned short u16;
typedef unsigned int u32;
using bf16x8 = __attribute__((ext_vector_type(8))) short;
using f32x4  = __attribute__((ext_vector_type(4))) float;

__device__ __forceinline__ u16 f2bf(float f) {
  u32 u = __float_as_uint(f);
  return (u16)((u + 0x7FFFu + ((u >> 16) & 1u)) >> 16);
}
__device__ __forceinline__ float bf2f(u16 h) {
  return __uint_as_float(((u32)h) << 16);
}

// ---------------- conv 3x3, 3->64, SAME, ReLU; out fmap[y][x][c] bf16 --------
__global__ __launch_bounds__(256) void conv3x3_relu_k(
    const float* __restrict__ img, const float* __restrict__ w,
    const float* __restrict__ bias, u16* __restrict__ fmap) {
  int p = blockIdx.x * 256 + threadIdx.x;  // 0..262143
  int y = p >> 9, x = p & 511;
  float v[27];
#pragma unroll
  for (int ci = 0; ci < 3; ++ci)
#pragma unroll
    for (int ky = 0; ky < 3; ++ky)
#pragma unroll
      for (int kx = 0; kx < 3; ++kx) {
        int yy = y + ky - 1, xx = x + kx - 1;
        bool ok = (yy >= 0) && (yy < 512) && (xx >= 0) && (xx < 512);
        v[(ci * 3 + ky) * 3 + kx] = ok ? img[ci * 262144 + yy * 512 + xx] : 0.f;
      }
  float acc[64];
#pragma unroll
  for (int co = 0; co < 64; ++co) {
    float s = bias[co];
#pragma unroll
    for (int q = 0; q < 27; ++q) s = fmaf(w[co * 27 + q], v[q], s);
    acc[co] = fmaxf(s, 0.f);
  }
  uint4* dst = (uint4*)((u32*)fmap + (size_t)p * 32);
#pragma unroll
  for (int q = 0; q < 8; ++q) {
    uint4 d;
    d.x = (u32)f2bf(acc[8 * q + 0]) | ((u32)f2bf(acc[8 * q + 1]) << 16);
    d.y = (u32)f2bf(acc[8 * q + 2]) | ((u32)f2bf(acc[8 * q + 3]) << 16);
    d.z = (u32)f2bf(acc[8 * q + 4]) | ((u32)f2bf(acc[8 * q + 5]) << 16);
    d.w = (u32)f2bf(acc[8 * q + 6]) | ((u32)f2bf(acc[8 * q + 7]) << 16);
    dst[q] = d;
  }
}

// ---------------- RoI max pool: block per roi; feat[n][c*49+py*7+px] bf16 ----
__global__ __launch_bounds__(256) void roipool_k(
    const u16* __restrict__ fmap, const int* __restrict__ regions,
    u16* __restrict__ feat) {
  int n = blockIdx.x, t = threadIdx.x;
  uint4* fdst = (uint4*)(feat + (size_t)n * 3136);  // 392 uint4 per row
  if (n >= 2000) {  // zero pad rows so GEMM needs no edge masking
    uint4 z; z.x = z.y = z.z = z.w = 0u;
    fdst[t % 392] = z;
    int t2 = t + 256; if (t2 < 392) fdst[t2] = z;
    if (t < 392) fdst[t] = z;
    return;
  }
  int r0 = regions[2 * n], c0 = regions[2 * n + 1];
  __shared__ uint2 rows_u2[1792];  // 4 rows x 28 x 64c bf16 = 14336 B
  __shared__ uint4 frow4[392];     // 3136 bf16 = 6272 B
  u16* rows = (u16*)rows_u2;
  u16* frow = (u16*)frow4;
  for (int py = 0; py < 7; ++py) {
#pragma unroll
    for (int q = 0; q < 7; ++q) {
      int cid = t + q * 256;           // 0..1791, 8B chunks
      int i = cid / 448, rem = cid % 448;
      int xo = rem >> 4, c4 = (rem & 15) << 2;
      int yy = r0 + py * 4 + i, xx = c0 + xo;
      rows_u2[cid] = *(const uint2*)(fmap + (((size_t)(yy * 512 + xx)) << 6) + c4);
    }
    __syncthreads();
#pragma unroll
    for (int h = 0; h < 2; ++h) {
      int o = t + h * 256;
      if (o < 448) {
        int c = o & 63, px = o >> 6;
        float best = -3.0e38f;
#pragma unroll
        for (int i = 0; i < 4; ++i)
#pragma unroll
          for (int j = 0; j < 4; ++j)
            best = fmaxf(best, bf2f(rows[(i * 28 + px * 4 + j) * 64 + c]));
        frow[c * 49 + py * 7 + px] = f2bf(best);
      }
    }
    __syncthreads();
  }
  if (t < 392) fdst[t] = frow4[t];
  int t2 = t + 256;
  if (t2 < 392) fdst[t2] = frow4[t2];
}

// ---------------- fp32 -> bf16 conversion (vectorized) -----------------------
__global__ __launch_bounds__(256) void f2bf_k(const float* __restrict__ in,
                                              u16* __restrict__ out, int n4) {
  int idx = blockIdx.x * 256 + threadIdx.x;
  int stride = gridDim.x * 256;
  for (int i = idx; i < n4; i += stride) {
    float4 v = ((const float4*)in)[i];
    uint2 o;
    o.x = (u32)f2bf(v.x) | ((u32)f2bf(v.y) << 16);
    o.y = (u32)f2bf(v.z) | ((u32)f2bf(v.w) << 16);
    ((uint2*)out)[i] = o;
  }
}

// ---------------- 8-wave pipelined bf16 GEMM (B^T), single phase per K-tile:
// C[m][n] = relu(sum_k A[m][k]*B[n][k] + bias[n]).
// BM=128, BN=256, BK=64. 512 thr = 8 waves (2x4), per-wave 64x64 out.
// 3 LDS buffers (144 KB), prefetch distance 2, counted vmcnt(6).
// T2 XOR-swizzle: LDS[row][slot16] holds global slot (slot ^ (row&7)).
// Per tile: {6 G2L issue; 16 ds_read; barrier; lgkm(0); 32 MFMA; vmcnt(6); barrier}
__global__ __launch_bounds__(512, 2) void gemm8_bt_relu_k(
    const u16* __restrict__ A, const u16* __restrict__ B,
    const float* __restrict__ bias, u16* __restrict__ C, int N, int K) {
  __shared__ uint4 lds4[9216];  // 3 * (128*64 + 256*64) bf16 = 147456 B
  char* ldsb = (char*)lds4;
  const int t = threadIdx.x;
  const int lane = t & 63, wv = t >> 6;
  const int wm = wv >> 2, wn = wv & 3;

  int bid = blockIdx.x;                      // grid must be exactly 256
  int swz = ((bid & 7) << 5) | (bid >> 3);   // XCD-contiguous remap (bijective)
  const int nb = swz >> 4, mb = swz & 15;
  const int m0 = mb * 128, n0 = nb * 256;

  const u16* __restrict__ Ab = A + (size_t)m0 * K;
  const u16* __restrict__ Bb = B + (size_t)n0 * K;

  // staging: per-thread source with pre-applied inverse swizzle (rule #21)
  const int srow = t >> 3;                   // 0..63 row within a sweep
  const int sslot = (t & 7) ^ (srow & 7);    // permuted 16B slot in the row
  const u16* pA0 = Ab + (size_t)srow * K + sslot * 8;
  const u16* pA1 = pA0 + (size_t)64 * K;
  const u16* pB0 = Bb + (size_t)srow * K + sslot * 8;
  const u16* pB1 = pB0 + (size_t)64 * K;
  const u16* pB2 = pB0 + (size_t)128 * K;
  const u16* pB3 = pB0 + (size_t)192 * K;
  const int dof = t * 16;                    // linear LDS dest byte in sweep

#define G2L(src, ldst)                                                        \
  __builtin_amdgcn_global_load_lds(                                          \
      (const __attribute__((address_space(1))) void*)(src),                  \
      (__attribute__((address_space(3))) void*)(ldst), 16, 0, 0)

  // frag read addressing (swizzled)
  const int rA = wm * 64 + (lane & 15);
  const int rB = wn * 64 + (lane & 15);
  const int sl = lane >> 4;  // 0..3
#define LOFF(r, slot) (((r) << 7) + ((((slot) ^ ((r) & 7))) << 4))

  f32x4 acc[4][4] = {};
  bf16x8 afr[4][2], bfr[4][2];

  const int NT = K >> 6;
  // ---- prologue: stage tiles 0 and 1
  {
    char* A0 = ldsb; char* B0 = A0 + 16384;
    char* A1 = ldsb + 49152; char* B1 = A1 + 16384;
    G2L(pA0, A0 + dof); G2L(pA1, A0 + 8192 + dof);
    G2L(pB0, B0 + dof); G2L(pB1, B0 + 8192 + dof);
    G2L(pB2, B0 + 16384 + dof); G2L(pB3, B0 + 24576 + dof);
    G2L(pA0 + 64, A1 + dof); G2L(pA1 + 64, A1 + 8192 + dof);
    G2L(pB0 + 64, B1 + dof); G2L(pB1 + 64, B1 + 8192 + dof);
    G2L(pB2 + 64, B1 + 16384 + dof); G2L(pB3 + 64, B1 + 24576 + dof);
  }
  asm volatile("s_waitcnt vmcnt(6)" ::: "memory");  // tile 0 landed
  __builtin_amdgcn_s_barrier();

  int cb = 0;  // current buffer = tt % 3
  for (int tt = 0; tt < NT; ++tt) {
    const int pb = (cb + 2 >= 3) ? cb - 1 : cb + 2;  // (tt+2)%3
    const bool pf = (tt + 2) < NT;
    char* Acur = ldsb + cb * 49152; char* Bcur = Acur + 16384;
    char* Apf  = ldsb + pb * 49152; char* Bpf  = Apf + 16384;
    const int kof = (tt + 2) << 6;

    // issue prefetch for tile tt+2 first (hide HBM latency under this tile)
    if (pf) {
      G2L(pA0 + kof, Apf + dof);
      G2L(pA1 + kof, Apf + 8192 + dof);
      G2L(pB0 + kof, Bpf + dof);
      G2L(pB1 + kof, Bpf + 8192 + dof);
      G2L(pB2 + kof, Bpf + 16384 + dof);
      G2L(pB3 + kof, Bpf + 24576 + dof);
    }
    // read all fragments for this tile (16 x ds_read_b128)
#pragma unroll
    for (int j = 0; j < 4; ++j) {
      bfr[j][0] = *(const bf16x8*)(Bcur + LOFF(rB + j * 16, sl));
      bfr[j][1] = *(const bf16x8*)(Bcur + LOFF(rB + j * 16, 4 + sl));
    }
#pragma unroll
    for (int i = 0; i < 4; ++i) {
      afr[i][0] = *(const bf16x8*)(Acur + LOFF(rA + i * 16, sl));
      afr[i][1] = *(const bf16x8*)(Acur + LOFF(rA + i * 16, 4 + sl));
    }
    __builtin_amdgcn_s_barrier();
    asm volatile("s_waitcnt lgkmcnt(0)" ::: "memory");
    __builtin_amdgcn_sched_barrier(0);
    __builtin_amdgcn_s_setprio(1);
#pragma unroll
    for (int i = 0; i < 4; ++i)
#pragma unroll
      for (int j = 0; j < 4; ++j) {
        acc[i][j] = __builtin_amdgcn_mfma_f32_16x16x32_bf16(afr[i][0], bfr[j][0], acc[i][j], 0, 0, 0);
        acc[i][j] = __builtin_amdgcn_mfma_f32_16x16x32_bf16(afr[i][1], bfr[j][1], acc[i][j], 0, 0, 0);
      }
    __builtin_amdgcn_s_setprio(0);
    // tile boundary: tile tt+1 must be resident before next iteration reads it
    if (pf) {
      asm volatile("s_waitcnt vmcnt(6)" ::: "memory");   // keep tt+2 in flight
    } else if (tt + 1 < NT) {
      asm volatile("s_waitcnt vmcnt(0)" ::: "memory");   // drain tail
    }
    __builtin_amdgcn_s_barrier();
    cb = (cb == 2) ? 0 : cb + 1;
  }
#undef G2L
#undef LOFF

  // ---- epilogue: bias + relu + bf16 store
  float bv[4];
#pragma unroll
  for (int j = 0; j < 4; ++j) bv[j] = bias[n0 + wn * 64 + j * 16 + (lane & 15)];
#pragma unroll
  for (int i = 0; i < 4; ++i)
#pragma unroll
    for (int j = 0; j < 4; ++j) {
      int cg = n0 + wn * 64 + j * 16 + (lane & 15);
#pragma unroll
      for (int r = 0; r < 4; ++r) {
        int rg = m0 + wm * 64 + i * 16 + (lane >> 4) * 4 + r;
        float v = fmaxf(acc[i][j][r] + bv[j], 0.f);
        C[(size_t)rg * N + cg] = f2bf(v);
      }
    }
}

// ---------------- cls/bbox heads: block per roi, 10 dots of K=4096 -----------
__global__ __launch_bounds__(256) void heads_k(
    const u16* __restrict__ h2, const float* __restrict__ cw,
    const float* __restrict__ cb, const float* __restrict__ bw,
    const float* __restrict__ bb, float* __restrict__ out) {
  int m = blockIdx.x, t = threadIdx.x;
  const u16* hrow = h2 + (size_t)m * 4096;
  float p[10];
#pragma unroll
  for (int j = 0; j < 10; ++j) p[j] = 0.f;
  for (int k = t; k < 4096; k += 256) {
    float v = bf2f(hrow[k]);
    p[0] = fmaf(v, cw[k], p[0]);
    p[1] = fmaf(v, cw[4096 + k], p[1]);
#pragma unroll
    for (int j = 0; j < 8; ++j) p[2 + j] = fmaf(v, bw[j * 4096 + k], p[2 + j]);
  }
#pragma unroll
  for (int j = 0; j < 10; ++j)
#pragma unroll
    for (int off = 32; off > 0; off >>= 1) p[j] += __shfl_down(p[j], off);
  __shared__ float red[4][10];
  int lane = t & 63, wv = t >> 6;
  if (lane == 0) {
#pragma unroll
    for (int j = 0; j < 10; ++j) red[wv][j] = p[j];
  }
  __syncthreads();
  if (t < 10) {
    float s = red[0][t] + red[1][t] + red[2][t] + red[3][t];
    s += (t < 2) ? cb[t] : bb[t - 2];
    if (t < 2) out[m * 2 + t] = s;
    else out[4000 + m * 8 + (t - 2)] = s;
  }
}

extern "C" void kernel_launch(void* const* d_in, const int* in_sizes, int n_in,
                              void* d_out, int out_size, void* d_ws, size_t ws_size,
                              hipStream_t stream) {
  const float* img    = (const float*)d_in[0];
  const int*   regions= (const int*)d_in[1];
  const float* conv_w = (const float*)d_in[2];
  const float* conv_b = (const float*)d_in[3];
  const float* fc1_w  = (const float*)d_in[4];
  const float* fc1_b  = (const float*)d_in[5];
  const float* fc2_w  = (const float*)d_in[6];
  const float* fc2_b  = (const float*)d_in[7];
  const float* cls_w  = (const float*)d_in[8];
  const float* cls_b  = (const float*)d_in[9];
  const float* bbox_w = (const float*)d_in[10];
  const float* bbox_b = (const float*)d_in[11];
  float* out = (float*)d_out;

  char* ws = (char*)d_ws;
  // layout (bytes):
  //   [0, 33554432)          fmap  [512][512][64] bf16   (later reused: h1, h2)
  //   [33554432, 46399488)   feat  [2048][3136] bf16
  //   [46399488, 72089600)   w1b   [4096][3136] bf16
  //   [72089600, 105644032)  w2b   [4096][4096] bf16
  u16* fmap = (u16*)(ws);
  u16* feat = (u16*)(ws + 33554432);
  u16* w1b  = (u16*)(ws + 46399488);
  u16* w2b  = (u16*)(ws + 72089600);
  u16* h1   = (u16*)(ws);              // aliases fmap (dead after pooling)
  u16* h2   = (u16*)(ws + 16777216);   // second half of fmap region

  conv3x3_relu_k<<<1024, 256, 0, stream>>>(img, conv_w, conv_b, fmap);
  roipool_k<<<2048, 256, 0, stream>>>(fmap, regions, feat);
  f2bf_k<<<2048, 256, 0, stream>>>(fc1_w, w1b, 4096 * 3136 / 4);
  f2bf_k<<<2048, 256, 0, stream>>>(fc2_w, w2b, 4096 * 4096 / 4);
  gemm8_bt_relu_k<<<256, 512, 0, stream>>>(feat, w1b, fc1_b, h1, 4096, 3136);
  gemm8_bt_relu_k<<<256, 512, 0, stream>>>(h1, w2b, fc2_b, h2, 4096, 4096);
  heads_k<<<2000, 256, 0, stream>>>(h2, cls_w, cls_b, bbox_w, bbox_b, out);
}

// Round 7
// 229.309 us; speedup vs baseline: 1.5566x; 1.0421x over previous
//
#include <hip/hip_runtime.h>

typedef unsigned short u16;
typedef unsigned int u32;
using bf16x8 = __attribute__((ext_vector_type(8))) short;
using f32x4  = __attribute__((ext_vector_type(4))) float;

__device__ __forceinline__ u16 f2bf(float f) {
  u32 u = __float_as_uint(f);
  return (u16)((u + 0x7FFFu + ((u >> 16) & 1u)) >> 16);
}
__device__ __forceinline__ float bf2f(u16 h) {
  return __uint_as_float(((u32)h) << 16);
}

// ---------------- conv 3x3, 3->64, SAME, ReLU; out fmap[y][x][c] bf16 --------
__global__ __launch_bounds__(256) void conv3x3_relu_k(
    const float* __restrict__ img, const float* __restrict__ w,
    const float* __restrict__ bias, u16* __restrict__ fmap) {
  int p = blockIdx.x * 256 + threadIdx.x;  // 0..262143
  int y = p >> 9, x = p & 511;
  float v[27];
#pragma unroll
  for (int ci = 0; ci < 3; ++ci)
#pragma unroll
    for (int ky = 0; ky < 3; ++ky)
#pragma unroll
      for (int kx = 0; kx < 3; ++kx) {
        int yy = y + ky - 1, xx = x + kx - 1;
        bool ok = (yy >= 0) && (yy < 512) && (xx >= 0) && (xx < 512);
        v[(ci * 3 + ky) * 3 + kx] = ok ? img[ci * 262144 + yy * 512 + xx] : 0.f;
      }
  float acc[64];
#pragma unroll
  for (int co = 0; co < 64; ++co) {
    float s = bias[co];
#pragma unroll
    for (int q = 0; q < 27; ++q) s = fmaf(w[co * 27 + q], v[q], s);
    acc[co] = fmaxf(s, 0.f);
  }
  uint4* dst = (uint4*)((u32*)fmap + (size_t)p * 32);
#pragma unroll
  for (int q = 0; q < 8; ++q) {
    uint4 d;
    d.x = (u32)f2bf(acc[8 * q + 0]) | ((u32)f2bf(acc[8 * q + 1]) << 16);
    d.y = (u32)f2bf(acc[8 * q + 2]) | ((u32)f2bf(acc[8 * q + 3]) << 16);
    d.z = (u32)f2bf(acc[8 * q + 4]) | ((u32)f2bf(acc[8 * q + 5]) << 16);
    d.w = (u32)f2bf(acc[8 * q + 6]) | ((u32)f2bf(acc[8 * q + 7]) << 16);
    dst[q] = d;
  }
}

// ---------------- RoI max pool: block per roi; feat[n][c*49+py*7+px] bf16 ----
__global__ __launch_bounds__(256) void roipool_k(
    const u16* __restrict__ fmap, const int* __restrict__ regions,
    u16* __restrict__ feat) {
  int n = blockIdx.x, t = threadIdx.x;
  uint4* fdst = (uint4*)(feat + (size_t)n * 3136);  // 392 uint4 per row
  if (n >= 2000) {  // zero pad rows so GEMM needs no edge masking
    uint4 z; z.x = z.y = z.z = z.w = 0u;
    fdst[t % 392] = z;
    int t2 = t + 256; if (t2 < 392) fdst[t2] = z;
    if (t < 392) fdst[t] = z;
    return;
  }
  int r0 = regions[2 * n], c0 = regions[2 * n + 1];
  __shared__ uint2 rows_u2[1792];  // 4 rows x 28 x 64c bf16 = 14336 B
  __shared__ uint4 frow4[392];     // 3136 bf16 = 6272 B
  u16* rows = (u16*)rows_u2;
  u16* frow = (u16*)frow4;
  for (int py = 0; py < 7; ++py) {
#pragma unroll
    for (int q = 0; q < 7; ++q) {
      int cid = t + q * 256;           // 0..1791, 8B chunks
      int i = cid / 448, rem = cid % 448;
      int xo = rem >> 4, c4 = (rem & 15) << 2;
      int yy = r0 + py * 4 + i, xx = c0 + xo;
      rows_u2[cid] = *(const uint2*)(fmap + (((size_t)(yy * 512 + xx)) << 6) + c4);
    }
    __syncthreads();
#pragma unroll
    for (int h = 0; h < 2; ++h) {
      int o = t + h * 256;
      if (o < 448) {
        int c = o & 63, px = o >> 6;
        float best = -3.0e38f;
#pragma unroll
        for (int i = 0; i < 4; ++i)
#pragma unroll
          for (int j = 0; j < 4; ++j)
            best = fmaxf(best, bf2f(rows[(i * 28 + px * 4 + j) * 64 + c]));
        frow[c * 49 + py * 7 + px] = f2bf(best);
      }
    }
    __syncthreads();
  }
  if (t < 392) fdst[t] = frow4[t];
  int t2 = t + 256;
  if (t2 < 392) fdst[t2] = frow4[t2];
}

// ---------------- fp32 -> bf16 conversion (vectorized) -----------------------
__global__ __launch_bounds__(256) void f2bf_k(const float* __restrict__ in,
                                              u16* __restrict__ out, int n4) {
  int idx = blockIdx.x * 256 + threadIdx.x;
  int stride = gridDim.x * 256;
  for (int i = idx; i < n4; i += stride) {
    float4 v = ((const float4*)in)[i];
    uint2 o;
    o.x = (u32)f2bf(v.x) | ((u32)f2bf(v.y) << 16);
    o.y = (u32)f2bf(v.z) | ((u32)f2bf(v.w) << 16);
    ((uint2*)out)[i] = o;
  }
}

// ---------------- 8-wave pipelined bf16 GEMM (B^T), template-minimum loop:
// per K-tile: {STAGE(t+2); [sched fence]; ds_read + MFMA compiler-coscheduled;
//              vmcnt(6); ONE barrier}.  No mid-tile barrier, no manual lgkm
// drain (compiler emits fine-grained lgkmcnt before each MFMA use).
// BM=128, BN=256, BK=64. 512 thr = 8 waves (2x4), per-wave 64x64 out.
// 3 LDS buffers (144 KB), prefetch distance 2, counted vmcnt(6).
// T2 XOR-swizzle: LDS[row][slot16] holds global slot (slot ^ (row&7)).
__global__ __launch_bounds__(512, 2) void gemm8_bt_relu_k(
    const u16* __restrict__ A, const u16* __restrict__ B,
    const float* __restrict__ bias, u16* __restrict__ C, int N, int K) {
  __shared__ uint4 lds4[9216];  // 3 * (128*64 + 256*64) bf16 = 147456 B
  char* ldsb = (char*)lds4;
  const int t = threadIdx.x;
  const int lane = t & 63, wv = t >> 6;
  const int wm = wv >> 2, wn = wv & 3;

  int bid = blockIdx.x;                      // grid must be exactly 256
  int swz = ((bid & 7) << 5) | (bid >> 3);   // XCD-contiguous remap (bijective)
  const int nb = swz >> 4, mb = swz & 15;
  const int m0 = mb * 128, n0 = nb * 256;

  const u16* __restrict__ Ab = A + (size_t)m0 * K;
  const u16* __restrict__ Bb = B + (size_t)n0 * K;

  // staging: per-thread source with pre-applied inverse swizzle (rule #21)
  const int srow = t >> 3;                   // 0..63 row within a sweep
  const int sslot = (t & 7) ^ (srow & 7);    // permuted 16B slot in the row
  const u16* pA0 = Ab + (size_t)srow * K + sslot * 8;
  const u16* pA1 = pA0 + (size_t)64 * K;
  const u16* pB0 = Bb + (size_t)srow * K + sslot * 8;
  const u16* pB1 = pB0 + (size_t)64 * K;
  const u16* pB2 = pB0 + (size_t)128 * K;
  const u16* pB3 = pB0 + (size_t)192 * K;
  const int dof = t * 16;                    // linear LDS dest byte in sweep

#define G2L(src, ldst)                                                        \
  __builtin_amdgcn_global_load_lds(                                          \
      (const __attribute__((address_space(1))) void*)(src),                  \
      (__attribute__((address_space(3))) void*)(ldst), 16, 0, 0)

  // frag read addressing (swizzled)
  const int rA = wm * 64 + (lane & 15);
  const int rB = wn * 64 + (lane & 15);
  const int sl = lane >> 4;  // 0..3
#define LOFF(r, slot) (((r) << 7) + ((((slot) ^ ((r) & 7))) << 4))

  f32x4 acc[4][4] = {};
  bf16x8 afr[4][2], bfr[4][2];

  const int NT = K >> 6;
  // ---- prologue: stage tiles 0 and 1
  {
    char* A0 = ldsb; char* B0 = A0 + 16384;
    char* A1 = ldsb + 49152; char* B1 = A1 + 16384;
    G2L(pA0, A0 + dof); G2L(pA1, A0 + 8192 + dof);
    G2L(pB0, B0 + dof); G2L(pB1, B0 + 8192 + dof);
    G2L(pB2, B0 + 16384 + dof); G2L(pB3, B0 + 24576 + dof);
    G2L(pA0 + 64, A1 + dof); G2L(pA1 + 64, A1 + 8192 + dof);
    G2L(pB0 + 64, B1 + dof); G2L(pB1 + 64, B1 + 8192 + dof);
    G2L(pB2 + 64, B1 + 16384 + dof); G2L(pB3 + 64, B1 + 24576 + dof);
  }
  asm volatile("s_waitcnt vmcnt(6)" ::: "memory");  // tile 0 landed
  __builtin_amdgcn_s_barrier();

  int cb = 0;  // current buffer = tt % 3
  for (int tt = 0; tt < NT; ++tt) {
    const int pb = (cb + 2 >= 3) ? cb - 1 : cb + 2;  // (tt+2)%3
    const bool pf = (tt + 2) < NT;
    char* Acur = ldsb + cb * 49152; char* Bcur = Acur + 16384;
    char* Apf  = ldsb + pb * 49152; char* Bpf  = Apf + 16384;
    const int kof = (tt + 2) << 6;

    // issue prefetch for tile tt+2 first (hide HBM latency under this tile)
    if (pf) {
      G2L(pA0 + kof, Apf + dof);
      G2L(pA1 + kof, Apf + 8192 + dof);
      G2L(pB0 + kof, Bpf + dof);
      G2L(pB1 + kof, Bpf + 8192 + dof);
      G2L(pB2 + kof, Bpf + 16384 + dof);
      G2L(pB3 + kof, Bpf + 24576 + dof);
    }
    __builtin_amdgcn_sched_barrier(0);  // pin G2L issue before compute region
    __builtin_amdgcn_s_setprio(1);
    // ds_read + MFMA, compiler-coscheduled with incremental lgkm waits
#pragma unroll
    for (int j = 0; j < 4; ++j) {
      bfr[j][0] = *(const bf16x8*)(Bcur + LOFF(rB + j * 16, sl));
      bfr[j][1] = *(const bf16x8*)(Bcur + LOFF(rB + j * 16, 4 + sl));
    }
#pragma unroll
    for (int i = 0; i < 4; ++i) {
      afr[i][0] = *(const bf16x8*)(Acur + LOFF(rA + i * 16, sl));
      afr[i][1] = *(const bf16x8*)(Acur + LOFF(rA + i * 16, 4 + sl));
    }
#pragma unroll
    for (int i = 0; i < 4; ++i)
#pragma unroll
      for (int j = 0; j < 4; ++j) {
        acc[i][j] = __builtin_amdgcn_mfma_f32_16x16x32_bf16(afr[i][0], bfr[j][0], acc[i][j], 0, 0, 0);
        acc[i][j] = __builtin_amdgcn_mfma_f32_16x16x32_bf16(afr[i][1], bfr[j][1], acc[i][j], 0, 0, 0);
      }
    __builtin_amdgcn_s_setprio(0);
    // tile boundary: tile tt+1 must be fully resident before next iteration.
    // (asm memory clobber also fences the compiler from hoisting next tile's
    //  ds_reads above this point.)
    if (pf) {
      asm volatile("s_waitcnt vmcnt(6)" ::: "memory");   // keep tt+2 in flight
    } else if (tt + 1 < NT) {
      asm volatile("s_waitcnt vmcnt(0)" ::: "memory");   // drain tail
    }
    __builtin_amdgcn_s_barrier();
    cb = (cb == 2) ? 0 : cb + 1;
  }
#undef G2L
#undef LOFF

  // ---- epilogue: bias + relu + bf16 store
  float bv[4];
#pragma unroll
  for (int j = 0; j < 4; ++j) bv[j] = bias[n0 + wn * 64 + j * 16 + (lane & 15)];
#pragma unroll
  for (int i = 0; i < 4; ++i)
#pragma unroll
    for (int j = 0; j < 4; ++j) {
      int cg = n0 + wn * 64 + j * 16 + (lane & 15);
#pragma unroll
      for (int r = 0; r < 4; ++r) {
        int rg = m0 + wm * 64 + i * 16 + (lane >> 4) * 4 + r;
        float v = fmaxf(acc[i][j][r] + bv[j], 0.f);
        C[(size_t)rg * N + cg] = f2bf(v);
      }
    }
}

// ---------------- cls/bbox heads: block per roi, 10 dots of K=4096 -----------
__global__ __launch_bounds__(256) void heads_k(
    const u16* __restrict__ h2, const float* __restrict__ cw,
    const float* __restrict__ cb, const float* __restrict__ bw,
    const float* __restrict__ bb, float* __restrict__ out) {
  int m = blockIdx.x, t = threadIdx.x;
  const u16* hrow = h2 + (size_t)m * 4096;
  float p[10];
#pragma unroll
  for (int j = 0; j < 10; ++j) p[j] = 0.f;
  for (int k = t; k < 4096; k += 256) {
    float v = bf2f(hrow[k]);
    p[0] = fmaf(v, cw[k], p[0]);
    p[1] = fmaf(v, cw[4096 + k], p[1]);
#pragma unroll
    for (int j = 0; j < 8; ++j) p[2 + j] = fmaf(v, bw[j * 4096 + k], p[2 + j]);
  }
#pragma unroll
  for (int j = 0; j < 10; ++j)
#pragma unroll
    for (int off = 32; off > 0; off >>= 1) p[j] += __shfl_down(p[j], off);
  __shared__ float red[4][10];
  int lane = t & 63, wv = t >> 6;
  if (lane == 0) {
#pragma unroll
    for (int j = 0; j < 10; ++j) red[wv][j] = p[j];
  }
  __syncthreads();
  if (t < 10) {
    float s = red[0][t] + red[1][t] + red[2][t] + red[3][t];
    s += (t < 2) ? cb[t] : bb[t - 2];
    if (t < 2) out[m * 2 + t] = s;
    else out[4000 + m * 8 + (t - 2)] = s;
  }
}

extern "C" void kernel_launch(void* const* d_in, const int* in_sizes, int n_in,
                              void* d_out, int out_size, void* d_ws, size_t ws_size,
                              hipStream_t stream) {
  const float* img    = (const float*)d_in[0];
  const int*   regions= (const int*)d_in[1];
  const float* conv_w = (const float*)d_in[2];
  const float* conv_b = (const float*)d_in[3];
  const float* fc1_w  = (const float*)d_in[4];
  const float* fc1_b  = (const float*)d_in[5];
  const float* fc2_w  = (const float*)d_in[6];
  const float* fc2_b  = (const float*)d_in[7];
  const float* cls_w  = (const float*)d_in[8];
  const float* cls_b  = (const float*)d_in[9];
  const float* bbox_w = (const float*)d_in[10];
  const float* bbox_b = (const float*)d_in[11];
  float* out = (float*)d_out;

  char* ws = (char*)d_ws;
  // layout (bytes):
  //   [0, 33554432)          fmap  [512][512][64] bf16   (later reused: h1, h2)
  //   [33554432, 46399488)   feat  [2048][3136] bf16
  //   [46399488, 72089600)   w1b   [4096][3136] bf16
  //   [72089600, 105644032)  w2b   [4096][4096] bf16
  u16* fmap = (u16*)(ws);
  u16* feat = (u16*)(ws + 33554432);
  u16* w1b  = (u16*)(ws + 46399488);
  u16* w2b  = (u16*)(ws + 72089600);
  u16* h1   = (u16*)(ws);              // aliases fmap (dead after pooling)
  u16* h2   = (u16*)(ws + 16777216);   // second half of fmap region

  conv3x3_relu_k<<<1024, 256, 0, stream>>>(img, conv_w, conv_b, fmap);
  roipool_k<<<2048, 256, 0, stream>>>(fmap, regions, feat);
  f2bf_k<<<2048, 256, 0, stream>>>(fc1_w, w1b, 4096 * 3136 / 4);
  f2bf_k<<<2048, 256, 0, stream>>>(fc2_w, w2b, 4096 * 4096 / 4);
  gemm8_bt_relu_k<<<256, 512, 0, stream>>>(feat, w1b, fc1_b, h1, 4096, 3136);
  gemm8_bt_relu_k<<<256, 512, 0, stream>>>(h1, w2b, fc2_b, h2, 4096, 4096);
  heads_k<<<2000, 256, 0, stream>>>(h2, cls_w, cls_b, bbox_w, bbox_b, out);
}

// Round 8
// 224.894 us; speedup vs baseline: 1.5872x; 1.0196x over previous
//
#include <hip/hip_runtime.h>

typedef unsigned short u16;
typedef unsigned int u32;
using bf16x8 = __attribute__((ext_vector_type(8))) short;
using f32x4  = __attribute__((ext_vector_type(4))) float;
using ushort8 = __attribute__((ext_vector_type(8))) unsigned short;

__device__ __forceinline__ u16 f2bf(float f) {
  u32 u = __float_as_uint(f);
  return (u16)((u + 0x7FFFu + ((u >> 16) & 1u)) >> 16);
}
__device__ __forceinline__ float bf2f(u16 h) {
  return __uint_as_float(((u32)h) << 16);
}
// max of non-negative bf16 == unsigned 16-bit max (post-ReLU values only)
__device__ __forceinline__ ushort8 umax8(ushort8 a, ushort8 b) {
  return __builtin_elementwise_max(a, b);
}

// ---------------- conv 3x3, 3->64, SAME, ReLU; out fmap[y][x][c] bf16 --------
__global__ __launch_bounds__(256) void conv3x3_relu_k(
    const float* __restrict__ img, const float* __restrict__ w,
    const float* __restrict__ bias, u16* __restrict__ fmap) {
  int p = blockIdx.x * 256 + threadIdx.x;  // 0..262143
  int y = p >> 9, x = p & 511;
  float v[27];
#pragma unroll
  for (int ci = 0; ci < 3; ++ci)
#pragma unroll
    for (int ky = 0; ky < 3; ++ky)
#pragma unroll
      for (int kx = 0; kx < 3; ++kx) {
        int yy = y + ky - 1, xx = x + kx - 1;
        bool ok = (yy >= 0) && (yy < 512) && (xx >= 0) && (xx < 512);
        v[(ci * 3 + ky) * 3 + kx] = ok ? img[ci * 262144 + yy * 512 + xx] : 0.f;
      }
  float acc[64];
#pragma unroll
  for (int co = 0; co < 64; ++co) {
    float s = bias[co];
#pragma unroll
    for (int q = 0; q < 27; ++q) s = fmaf(w[co * 27 + q], v[q], s);
    acc[co] = fmaxf(s, 0.f);
  }
  uint4* dst = (uint4*)((u32*)fmap + (size_t)p * 32);
#pragma unroll
  for (int q = 0; q < 8; ++q) {
    uint4 d;
    d.x = (u32)f2bf(acc[8 * q + 0]) | ((u32)f2bf(acc[8 * q + 1]) << 16);
    d.y = (u32)f2bf(acc[8 * q + 2]) | ((u32)f2bf(acc[8 * q + 3]) << 16);
    d.z = (u32)f2bf(acc[8 * q + 4]) | ((u32)f2bf(acc[8 * q + 5]) << 16);
    d.w = (u32)f2bf(acc[8 * q + 6]) | ((u32)f2bf(acc[8 * q + 7]) << 16);
    dst[q] = d;
  }
}

// ---------------- vertical 4-row running max: M1[y][x][c] = max fmap[y..y+3] -
// thread g: cg = g&7 (16B channel chunk), x = (g>>3)&511, ych = g>>12 (64 rows)
// consecutive lanes cover contiguous 128B lines -> fully coalesced.
__global__ __launch_bounds__(256) void vmax_k(
    const u16* __restrict__ fmap, u16* __restrict__ M1) {
  int g = blockIdx.x * 256 + threadIdx.x;  // 0..32767
  int cg = g & 7, x = (g >> 3) & 511, ych = g >> 12;
  int y0 = ych * 64;
  ushort8 h0, h1, h2;
  for (int i = 0; i < 67; ++i) {
    int yy = y0 + i; if (yy > 511) yy = 511;
    ushort8 r = *(const ushort8*)(fmap + (((size_t)(yy * 512 + x)) << 6) + cg * 8);
    if (i >= 3) {
      ushort8 m = umax8(umax8(h0, h1), umax8(h2, r));
      *(ushort8*)(M1 + (((size_t)((y0 + i - 3) * 512 + x)) << 6) + cg * 8) = m;
    }
    h0 = h1; h1 = h2; h2 = r;
  }
}

// ---------------- RoI pool gather: bin = max over 4 cols of one M1 row -------
// feat[n][c*49 + py*7 + px] bf16; rows n>=2000 zeroed (GEMM pad).
__global__ __launch_bounds__(256) void roipool2_k(
    const u16* __restrict__ M1, const int* __restrict__ regions,
    u16* __restrict__ feat) {
  int n = blockIdx.x, t = threadIdx.x;
  uint4* fdst = (uint4*)(feat + (size_t)n * 3136);  // 392 uint4 per row
  if (n >= 2000) {
    uint4 z; z.x = z.y = z.z = z.w = 0u;
    for (int w = t; w < 392; w += 256) fdst[w] = z;
    return;
  }
  __shared__ u16 frow[3136];
  int r0 = regions[2 * n], c0 = regions[2 * n + 1];
  for (int w = t; w < 392; w += 256) {  // 49 bins x 8 channel-chunks
    int bin = w >> 3, cg = w & 7;
    int py = bin / 7, px = bin % 7;
    int y = r0 + py * 4, xb = c0 + px * 4;
    const u16* base = M1 + (((size_t)(y * 512 + xb)) << 6) + cg * 8;
    ushort8 a = *(const ushort8*)(base);
    ushort8 b = *(const ushort8*)(base + 64);
    ushort8 c = *(const ushort8*)(base + 128);
    ushort8 d = *(const ushort8*)(base + 192);
    ushort8 m = umax8(umax8(a, b), umax8(c, d));
#pragma unroll
    for (int k = 0; k < 8; ++k) frow[(cg * 8 + k) * 49 + bin] = m[k];
  }
  __syncthreads();
  const uint4* fsrc = (const uint4*)frow;
  for (int w = t; w < 392; w += 256) fdst[w] = fsrc[w];
}

// ---------------- fp32 -> bf16 conversion (vectorized) -----------------------
__global__ __launch_bounds__(256) void f2bf_k(const float* __restrict__ in,
                                              u16* __restrict__ out, int n4) {
  int idx = blockIdx.x * 256 + threadIdx.x;
  int stride = gridDim.x * 256;
  for (int i = idx; i < n4; i += stride) {
    float4 v = ((const float4*)in)[i];
    uint2 o;
    o.x = (u32)f2bf(v.x) | ((u32)f2bf(v.y) << 16);
    o.y = (u32)f2bf(v.z) | ((u32)f2bf(v.w) << 16);
    ((uint2*)out)[i] = o;
  }
}

// ---------------- 8-wave pipelined bf16 GEMM (B^T), template-minimum loop ----
// (unchanged from R7: 71 us, MfmaUtil 38%, conflicts 0 — banked)
__global__ __launch_bounds__(512, 2) void gemm8_bt_relu_k(
    const u16* __restrict__ A, const u16* __restrict__ B,
    const float* __restrict__ bias, u16* __restrict__ C, int N, int K) {
  __shared__ uint4 lds4[9216];  // 3 * (128*64 + 256*64) bf16 = 147456 B
  char* ldsb = (char*)lds4;
  const int t = threadIdx.x;
  const int lane = t & 63, wv = t >> 6;
  const int wm = wv >> 2, wn = wv & 3;

  int bid = blockIdx.x;                      // grid must be exactly 256
  int swz = ((bid & 7) << 5) | (bid >> 3);   // XCD-contiguous remap (bijective)
  const int nb = swz >> 4, mb = swz & 15;
  const int m0 = mb * 128, n0 = nb * 256;

  const u16* __restrict__ Ab = A + (size_t)m0 * K;
  const u16* __restrict__ Bb = B + (size_t)n0 * K;

  const int srow = t >> 3;
  const int sslot = (t & 7) ^ (srow & 7);
  const u16* pA0 = Ab + (size_t)srow * K + sslot * 8;
  const u16* pA1 = pA0 + (size_t)64 * K;
  const u16* pB0 = Bb + (size_t)srow * K + sslot * 8;
  const u16* pB1 = pB0 + (size_t)64 * K;
  const u16* pB2 = pB0 + (size_t)128 * K;
  const u16* pB3 = pB0 + (size_t)192 * K;
  const int dof = t * 16;

#define G2L(src, ldst)                                                        \
  __builtin_amdgcn_global_load_lds(                                          \
      (const __attribute__((address_space(1))) void*)(src),                  \
      (__attribute__((address_space(3))) void*)(ldst), 16, 0, 0)

  const int rA = wm * 64 + (lane & 15);
  const int rB = wn * 64 + (lane & 15);
  const int sl = lane >> 4;
#define LOFF(r, slot) (((r) << 7) + ((((slot) ^ ((r) & 7))) << 4))

  f32x4 acc[4][4] = {};
  bf16x8 afr[4][2], bfr[4][2];

  const int NT = K >> 6;
  {
    char* A0 = ldsb; char* B0 = A0 + 16384;
    char* A1 = ldsb + 49152; char* B1 = A1 + 16384;
    G2L(pA0, A0 + dof); G2L(pA1, A0 + 8192 + dof);
    G2L(pB0, B0 + dof); G2L(pB1, B0 + 8192 + dof);
    G2L(pB2, B0 + 16384 + dof); G2L(pB3, B0 + 24576 + dof);
    G2L(pA0 + 64, A1 + dof); G2L(pA1 + 64, A1 + 8192 + dof);
    G2L(pB0 + 64, B1 + dof); G2L(pB1 + 64, B1 + 8192 + dof);
    G2L(pB2 + 64, B1 + 16384 + dof); G2L(pB3 + 64, B1 + 24576 + dof);
  }
  asm volatile("s_waitcnt vmcnt(6)" ::: "memory");
  __builtin_amdgcn_s_barrier();

  int cb = 0;
  for (int tt = 0; tt < NT; ++tt) {
    const int pb = (cb + 2 >= 3) ? cb - 1 : cb + 2;
    const bool pf = (tt + 2) < NT;
    char* Acur = ldsb + cb * 49152; char* Bcur = Acur + 16384;
    char* Apf  = ldsb + pb * 49152; char* Bpf  = Apf + 16384;
    const int kof = (tt + 2) << 6;

    if (pf) {
      G2L(pA0 + kof, Apf + dof);
      G2L(pA1 + kof, Apf + 8192 + dof);
      G2L(pB0 + kof, Bpf + dof);
      G2L(pB1 + kof, Bpf + 8192 + dof);
      G2L(pB2 + kof, Bpf + 16384 + dof);
      G2L(pB3 + kof, Bpf + 24576 + dof);
    }
    __builtin_amdgcn_sched_barrier(0);
    __builtin_amdgcn_s_setprio(1);
#pragma unroll
    for (int j = 0; j < 4; ++j) {
      bfr[j][0] = *(const bf16x8*)(Bcur + LOFF(rB + j * 16, sl));
      bfr[j][1] = *(const bf16x8*)(Bcur + LOFF(rB + j * 16, 4 + sl));
    }
#pragma unroll
    for (int i = 0; i < 4; ++i) {
      afr[i][0] = *(const bf16x8*)(Acur + LOFF(rA + i * 16, sl));
      afr[i][1] = *(const bf16x8*)(Acur + LOFF(rA + i * 16, 4 + sl));
    }
#pragma unroll
    for (int i = 0; i < 4; ++i)
#pragma unroll
      for (int j = 0; j < 4; ++j) {
        acc[i][j] = __builtin_amdgcn_mfma_f32_16x16x32_bf16(afr[i][0], bfr[j][0], acc[i][j], 0, 0, 0);
        acc[i][j] = __builtin_amdgcn_mfma_f32_16x16x32_bf16(afr[i][1], bfr[j][1], acc[i][j], 0, 0, 0);
      }
    __builtin_amdgcn_s_setprio(0);
    if (pf) {
      asm volatile("s_waitcnt vmcnt(6)" ::: "memory");
    } else if (tt + 1 < NT) {
      asm volatile("s_waitcnt vmcnt(0)" ::: "memory");
    }
    __builtin_amdgcn_s_barrier();
    cb = (cb == 2) ? 0 : cb + 1;
  }
#undef G2L
#undef LOFF

  float bv[4];
#pragma unroll
  for (int j = 0; j < 4; ++j) bv[j] = bias[n0 + wn * 64 + j * 16 + (lane & 15)];
#pragma unroll
  for (int i = 0; i < 4; ++i)
#pragma unroll
    for (int j = 0; j < 4; ++j) {
      int cg = n0 + wn * 64 + j * 16 + (lane & 15);
#pragma unroll
      for (int r = 0; r < 4; ++r) {
        int rg = m0 + wm * 64 + i * 16 + (lane >> 4) * 4 + r;
        float v = fmaxf(acc[i][j][r] + bv[j], 0.f);
        C[(size_t)rg * N + cg] = f2bf(v);
      }
    }
}

// ---------------- cls/bbox heads: block per roi, 10 dots of K=4096 -----------
__global__ __launch_bounds__(256) void heads_k(
    const u16* __restrict__ h2, const float* __restrict__ cw,
    const float* __restrict__ cb, const float* __restrict__ bw,
    const float* __restrict__ bb, float* __restrict__ out) {
  int m = blockIdx.x, t = threadIdx.x;
  const u16* hrow = h2 + (size_t)m * 4096;
  float p[10];
#pragma unroll
  for (int j = 0; j < 10; ++j) p[j] = 0.f;
  for (int k = t; k < 4096; k += 256) {
    float v = bf2f(hrow[k]);
    p[0] = fmaf(v, cw[k], p[0]);
    p[1] = fmaf(v, cw[4096 + k], p[1]);
#pragma unroll
    for (int j = 0; j < 8; ++j) p[2 + j] = fmaf(v, bw[j * 4096 + k], p[2 + j]);
  }
#pragma unroll
  for (int j = 0; j < 10; ++j)
#pragma unroll
    for (int off = 32; off > 0; off >>= 1) p[j] += __shfl_down(p[j], off);
  __shared__ float red[4][10];
  int lane = t & 63, wv = t >> 6;
  if (lane == 0) {
#pragma unroll
    for (int j = 0; j < 10; ++j) red[wv][j] = p[j];
  }
  __syncthreads();
  if (t < 10) {
    float s = red[0][t] + red[1][t] + red[2][t] + red[3][t];
    s += (t < 2) ? cb[t] : bb[t - 2];
    if (t < 2) out[m * 2 + t] = s;
    else out[4000 + m * 8 + (t - 2)] = s;
  }
}

extern "C" void kernel_launch(void* const* d_in, const int* in_sizes, int n_in,
                              void* d_out, int out_size, void* d_ws, size_t ws_size,
                              hipStream_t stream) {
  const float* img    = (const float*)d_in[0];
  const int*   regions= (const int*)d_in[1];
  const float* conv_w = (const float*)d_in[2];
  const float* conv_b = (const float*)d_in[3];
  const float* fc1_w  = (const float*)d_in[4];
  const float* fc1_b  = (const float*)d_in[5];
  const float* fc2_w  = (const float*)d_in[6];
  const float* fc2_b  = (const float*)d_in[7];
  const float* cls_w  = (const float*)d_in[8];
  const float* cls_b  = (const float*)d_in[9];
  const float* bbox_w = (const float*)d_in[10];
  const float* bbox_b = (const float*)d_in[11];
  float* out = (float*)d_out;

  char* ws = (char*)d_ws;
  // layout (bytes), total 105,644,032 (same footprint as before):
  //   [0, 33554432)          fmap [512][512][64] bf16; dead after vmax_k
  //                          -> h1 [0,16M), h2 [16M,32M)
  //   [33554432, 67108864)   M1 (vertical max); dead after roipool2_k
  //                          -> w2b [4096][4096] bf16 (f2bf2 runs after pool)
  //   [67108864, 79953920)   feat [2048][3136] bf16
  //   [79953920, 105644032)  w1b  [4096][3136] bf16
  u16* fmap = (u16*)(ws);
  u16* h1   = (u16*)(ws);
  u16* h2   = (u16*)(ws + 16777216);
  u16* M1   = (u16*)(ws + 33554432);
  u16* w2b  = (u16*)(ws + 33554432);
  u16* feat = (u16*)(ws + 67108864);
  u16* w1b  = (u16*)(ws + 79953920);

  conv3x3_relu_k<<<1024, 256, 0, stream>>>(img, conv_w, conv_b, fmap);
  vmax_k<<<128, 256, 0, stream>>>(fmap, M1);
  roipool2_k<<<2048, 256, 0, stream>>>(M1, regions, feat);
  f2bf_k<<<2048, 256, 0, stream>>>(fc1_w, w1b, 4096 * 3136 / 4);
  f2bf_k<<<2048, 256, 0, stream>>>(fc2_w, w2b, 4096 * 4096 / 4);
  gemm8_bt_relu_k<<<256, 512, 0, stream>>>(feat, w1b, fc1_b, h1, 4096, 3136);
  gemm8_bt_relu_k<<<256, 512, 0, stream>>>(h1, w2b, fc2_b, h2, 4096, 4096);
  heads_k<<<2000, 256, 0, stream>>>(h2, cls_w, cls_b, bbox_w, bbox_b, out);
}

// Round 9
// 222.698 us; speedup vs baseline: 1.6028x; 1.0099x over previous
//
#include <hip/hip_runtime.h>

typedef unsigned short u16;
typedef unsigned int u32;
using bf16x8 = __attribute__((ext_vector_type(8))) short;
using f32x4  = __attribute__((ext_vector_type(4))) float;
using ushort8 = __attribute__((ext_vector_type(8))) unsigned short;

__device__ __forceinline__ u16 f2bf(float f) {
  u32 u = __float_as_uint(f);
  return (u16)((u + 0x7FFFu + ((u >> 16) & 1u)) >> 16);
}
__device__ __forceinline__ float bf2f(u16 h) {
  return __uint_as_float(((u32)h) << 16);
}
__device__ __forceinline__ ushort8 umax8(ushort8 a, ushort8 b) {
  return __builtin_elementwise_max(a, b);
}

// ---------------- fused conv3x3(3->64)+ReLU + vertical 4-row max -> M1 -------
// M1[y][x][c] = max_{dy=0..3, y+dy<=511} relu(conv(img)[y+dy][x][c])  (bf16)
// (round(max(f)) == max(round(f)) since f2bf is monotone; padding rows are 0
//  and conv outputs are >=0 post-ReLU, so 0-padding the tail windows is exact)
// grid 1024 x 512thr: pxband = bx&15 (32 px), yband = bx>>4 (8 M1 rows).
// thread: x = pxband*32 + (t>>4), channels cq..cq+3 with cq = (t&15)*4.
// Writes: lane t&15 covers bytes (t&15)*8 of the 128B [y][x] line -> coalesced.
__global__ __launch_bounds__(512) void conv_vmax_k(
    const float* __restrict__ img, const float* __restrict__ w,
    const float* __restrict__ bias, u16* __restrict__ M1) {
  const int t = threadIdx.x;
  const int x = ((blockIdx.x & 15) << 5) + (t >> 4);
  const int cq = (t & 15) << 2;
  const int y0 = (blockIdx.x >> 4) << 3;

  float wr[27][4];
#pragma unroll
  for (int p = 0; p < 27; ++p)
#pragma unroll
    for (int c = 0; c < 4; ++c) wr[p][c] = w[(cq + c) * 27 + p];
  float bz[4];
#pragma unroll
  for (int c = 0; c < 4; ++c) bz[c] = bias[cq + c];

  const bool xm = (x > 0), xp = (x < 511);
  float win[3][3][3];  // [ci][slot 0..2 = rows r-1,r,r+1][kx]

#define LOADROW(yy, s)                                                        \
  do {                                                                        \
    if ((yy) >= 0 && (yy) <= 511) {                                          \
      _Pragma("unroll") for (int ci = 0; ci < 3; ++ci) {                      \
        const float* rp = img + ci * 262144 + (yy) * 512 + x;                 \
        win[ci][s][0] = xm ? rp[-1] : 0.f;                                    \
        win[ci][s][1] = rp[0];                                                \
        win[ci][s][2] = xp ? rp[1] : 0.f;                                     \
      }                                                                        \
    } else {                                                                   \
      _Pragma("unroll") for (int ci = 0; ci < 3; ++ci) {                      \
        win[ci][s][0] = 0.f; win[ci][s][1] = 0.f; win[ci][s][2] = 0.f;        \
      }                                                                        \
    }                                                                          \
  } while (0)

  LOADROW(y0 - 1, 0);
  LOADROW(y0, 1);

  float h0[4], h1[4], h2[4], cur[4];
#pragma unroll
  for (int i = 0; i < 11; ++i) {
    const int r = y0 + i;
    LOADROW(r + 1, 2);
    if (r <= 511) {
#pragma unroll
      for (int c = 0; c < 4; ++c) cur[c] = bz[c];
#pragma unroll
      for (int ci = 0; ci < 3; ++ci)
#pragma unroll
        for (int ky = 0; ky < 3; ++ky)
#pragma unroll
          for (int kx = 0; kx < 3; ++kx) {
            const float iv = win[ci][ky][kx];
            const int p = ci * 9 + ky * 3 + kx;
#pragma unroll
            for (int c = 0; c < 4; ++c) cur[c] = fmaf(wr[p][c], iv, cur[c]);
          }
#pragma unroll
      for (int c = 0; c < 4; ++c) cur[c] = fmaxf(cur[c], 0.f);
    } else {
#pragma unroll
      for (int c = 0; c < 4; ++c) cur[c] = 0.f;
    }
    if (i >= 3) {
      const int ym = r - 3;
      float m[4];
#pragma unroll
      for (int c = 0; c < 4; ++c)
        m[c] = fmaxf(fmaxf(h0[c], h1[c]), fmaxf(h2[c], cur[c]));
      uint2 o;
      o.x = (u32)f2bf(m[0]) | ((u32)f2bf(m[1]) << 16);
      o.y = (u32)f2bf(m[2]) | ((u32)f2bf(m[3]) << 16);
      *(uint2*)(M1 + (((size_t)(ym * 512 + x)) << 6) + cq) = o;
    }
#pragma unroll
    for (int c = 0; c < 4; ++c) { h0[c] = h1[c]; h1[c] = h2[c]; h2[c] = cur[c]; }
#pragma unroll
    for (int ci = 0; ci < 3; ++ci)
#pragma unroll
      for (int kx = 0; kx < 3; ++kx) {
        win[ci][0][kx] = win[ci][1][kx];
        win[ci][1][kx] = win[ci][2][kx];
      }
  }
#undef LOADROW
}

// ---------------- RoI pool gather: bin = max over 4 cols of one M1 row -------
__global__ __launch_bounds__(256) void roipool2_k(
    const u16* __restrict__ M1, const int* __restrict__ regions,
    u16* __restrict__ feat) {
  int n = blockIdx.x, t = threadIdx.x;
  uint4* fdst = (uint4*)(feat + (size_t)n * 3136);  // 392 uint4 per row
  if (n >= 2000) {
    uint4 z; z.x = z.y = z.z = z.w = 0u;
    for (int w = t; w < 392; w += 256) fdst[w] = z;
    return;
  }
  __shared__ u16 frow[3136];
  int r0 = regions[2 * n], c0 = regions[2 * n + 1];
  for (int w = t; w < 392; w += 256) {  // 49 bins x 8 channel-chunks
    int bin = w >> 3, cg = w & 7;
    int py = bin / 7, px = bin % 7;
    int y = r0 + py * 4, xb = c0 + px * 4;
    const u16* base = M1 + (((size_t)(y * 512 + xb)) << 6) + cg * 8;
    ushort8 a = *(const ushort8*)(base);
    ushort8 b = *(const ushort8*)(base + 64);
    ushort8 c = *(const ushort8*)(base + 128);
    ushort8 d = *(const ushort8*)(base + 192);
    ushort8 m = umax8(umax8(a, b), umax8(c, d));
#pragma unroll
    for (int k = 0; k < 8; ++k) frow[(cg * 8 + k) * 49 + bin] = m[k];
  }
  __syncthreads();
  const uint4* fsrc = (const uint4*)frow;
  for (int w = t; w < 392; w += 256) fdst[w] = fsrc[w];
}

// ---------------- fp32 -> bf16, two arrays in one launch ----------------------
__global__ __launch_bounds__(256) void f2bf2_k(
    const float* __restrict__ in1, u16* __restrict__ out1, int n4a,
    const float* __restrict__ in2, u16* __restrict__ out2, int n4total) {
  int idx = blockIdx.x * 256 + threadIdx.x;
  int stride = gridDim.x * 256;
  for (int i = idx; i < n4total; i += stride) {
    const float* in; u16* o16; int k;
    if (i < n4a) { in = in1; o16 = out1; k = i; }
    else         { in = in2; o16 = out2; k = i - n4a; }
    float4 v = ((const float4*)in)[k];
    uint2 o;
    o.x = (u32)f2bf(v.x) | ((u32)f2bf(v.y) << 16);
    o.y = (u32)f2bf(v.z) | ((u32)f2bf(v.w) << 16);
    ((uint2*)o16)[k] = o;
  }
}

// ---------------- 8-wave pipelined bf16 GEMM (B^T) — banked (R7, 71 us) ------
__global__ __launch_bounds__(512, 2) void gemm8_bt_relu_k(
    const u16* __restrict__ A, const u16* __restrict__ B,
    const float* __restrict__ bias, u16* __restrict__ C, int N, int K) {
  __shared__ uint4 lds4[9216];  // 3 * (128*64 + 256*64) bf16 = 147456 B
  char* ldsb = (char*)lds4;
  const int t = threadIdx.x;
  const int lane = t & 63, wv = t >> 6;
  const int wm = wv >> 2, wn = wv & 3;

  int bid = blockIdx.x;                      // grid must be exactly 256
  int swz = ((bid & 7) << 5) | (bid >> 3);   // XCD-contiguous remap (bijective)
  const int nb = swz >> 4, mb = swz & 15;
  const int m0 = mb * 128, n0 = nb * 256;

  const u16* __restrict__ Ab = A + (size_t)m0 * K;
  const u16* __restrict__ Bb = B + (size_t)n0 * K;

  const int srow = t >> 3;
  const int sslot = (t & 7) ^ (srow & 7);
  const u16* pA0 = Ab + (size_t)srow * K + sslot * 8;
  const u16* pA1 = pA0 + (size_t)64 * K;
  const u16* pB0 = Bb + (size_t)srow * K + sslot * 8;
  const u16* pB1 = pB0 + (size_t)64 * K;
  const u16* pB2 = pB0 + (size_t)128 * K;
  const u16* pB3 = pB0 + (size_t)192 * K;
  const int dof = t * 16;

#define G2L(src, ldst)                                                        \
  __builtin_amdgcn_global_load_lds(                                          \
      (const __attribute__((address_space(1))) void*)(src),                  \
      (__attribute__((address_space(3))) void*)(ldst), 16, 0, 0)

  const int rA = wm * 64 + (lane & 15);
  const int rB = wn * 64 + (lane & 15);
  const int sl = lane >> 4;
#define LOFF(r, slot) (((r) << 7) + ((((slot) ^ ((r) & 7))) << 4))

  f32x4 acc[4][4] = {};
  bf16x8 afr[4][2], bfr[4][2];

  const int NT = K >> 6;
  {
    char* A0 = ldsb; char* B0 = A0 + 16384;
    char* A1 = ldsb + 49152; char* B1 = A1 + 16384;
    G2L(pA0, A0 + dof); G2L(pA1, A0 + 8192 + dof);
    G2L(pB0, B0 + dof); G2L(pB1, B0 + 8192 + dof);
    G2L(pB2, B0 + 16384 + dof); G2L(pB3, B0 + 24576 + dof);
    G2L(pA0 + 64, A1 + dof); G2L(pA1 + 64, A1 + 8192 + dof);
    G2L(pB0 + 64, B1 + dof); G2L(pB1 + 64, B1 + 8192 + dof);
    G2L(pB2 + 64, B1 + 16384 + dof); G2L(pB3 + 64, B1 + 24576 + dof);
  }
  asm volatile("s_waitcnt vmcnt(6)" ::: "memory");
  __builtin_amdgcn_s_barrier();

  int cb = 0;
  for (int tt = 0; tt < NT; ++tt) {
    const int pb = (cb + 2 >= 3) ? cb - 1 : cb + 2;
    const bool pf = (tt + 2) < NT;
    char* Acur = ldsb + cb * 49152; char* Bcur = Acur + 16384;
    char* Apf  = ldsb + pb * 49152; char* Bpf  = Apf + 16384;
    const int kof = (tt + 2) << 6;

    if (pf) {
      G2L(pA0 + kof, Apf + dof);
      G2L(pA1 + kof, Apf + 8192 + dof);
      G2L(pB0 + kof, Bpf + dof);
      G2L(pB1 + kof, Bpf + 8192 + dof);
      G2L(pB2 + kof, Bpf + 16384 + dof);
      G2L(pB3 + kof, Bpf + 24576 + dof);
    }
    __builtin_amdgcn_sched_barrier(0);
    __builtin_amdgcn_s_setprio(1);
#pragma unroll
    for (int j = 0; j < 4; ++j) {
      bfr[j][0] = *(const bf16x8*)(Bcur + LOFF(rB + j * 16, sl));
      bfr[j][1] = *(const bf16x8*)(Bcur + LOFF(rB + j * 16, 4 + sl));
    }
#pragma unroll
    for (int i = 0; i < 4; ++i) {
      afr[i][0] = *(const bf16x8*)(Acur + LOFF(rA + i * 16, sl));
      afr[i][1] = *(const bf16x8*)(Acur + LOFF(rA + i * 16, 4 + sl));
    }
#pragma unroll
    for (int i = 0; i < 4; ++i)
#pragma unroll
      for (int j = 0; j < 4; ++j) {
        acc[i][j] = __builtin_amdgcn_mfma_f32_16x16x32_bf16(afr[i][0], bfr[j][0], acc[i][j], 0, 0, 0);
        acc[i][j] = __builtin_amdgcn_mfma_f32_16x16x32_bf16(afr[i][1], bfr[j][1], acc[i][j], 0, 0, 0);
      }
    __builtin_amdgcn_s_setprio(0);
    if (pf) {
      asm volatile("s_waitcnt vmcnt(6)" ::: "memory");
    } else if (tt + 1 < NT) {
      asm volatile("s_waitcnt vmcnt(0)" ::: "memory");
    }
    __builtin_amdgcn_s_barrier();
    cb = (cb == 2) ? 0 : cb + 1;
  }
#undef G2L
#undef LOFF

  float bv[4];
#pragma unroll
  for (int j = 0; j < 4; ++j) bv[j] = bias[n0 + wn * 64 + j * 16 + (lane & 15)];
#pragma unroll
  for (int i = 0; i < 4; ++i)
#pragma unroll
    for (int j = 0; j < 4; ++j) {
      int cg = n0 + wn * 64 + j * 16 + (lane & 15);
#pragma unroll
      for (int r = 0; r < 4; ++r) {
        int rg = m0 + wm * 64 + i * 16 + (lane >> 4) * 4 + r;
        float v = fmaxf(acc[i][j][r] + bv[j], 0.f);
        C[(size_t)rg * N + cg] = f2bf(v);
      }
    }
}

// ---------------- cls/bbox heads: 8 ROIs/block, LDS-staged bf16 weights ------
__global__ __launch_bounds__(256) void heads_k(
    const u16* __restrict__ h2, const float* __restrict__ cw,
    const float* __restrict__ cb, const float* __restrict__ bw,
    const float* __restrict__ bb, float* __restrict__ out) {
  __shared__ u16 wl[10][4096];  // 80 KB
  __shared__ float red[4][10];
  const int t = threadIdx.x;
  // stage weights once per block (f32 -> bf16)
  for (int i4 = t; i4 < 10240; i4 += 256) {
    int j = i4 >> 10, k4 = i4 & 1023;
    float4 v = (j < 2) ? ((const float4*)cw)[j * 1024 + k4]
                       : ((const float4*)bw)[(j - 2) * 1024 + k4];
    uint2 o;
    o.x = (u32)f2bf(v.x) | ((u32)f2bf(v.y) << 16);
    o.y = (u32)f2bf(v.z) | ((u32)f2bf(v.w) << 16);
    *(uint2*)(&wl[j][k4 * 4]) = o;
  }
  __syncthreads();
  const int lane = t & 63, wvi = t >> 6;
  const int m0 = blockIdx.x * 8;
  for (int mi = 0; mi < 8; ++mi) {
    const int m = m0 + mi;
    const u16* hrow = h2 + (size_t)m * 4096;
    float p[10];
#pragma unroll
    for (int j = 0; j < 10; ++j) p[j] = 0.f;
#pragma unroll
    for (int h = 0; h < 2; ++h) {
      const int kc = t + h * 256;  // 16B chunk index, 512 total
      ushort8 hv = ((const ushort8*)hrow)[kc];
      float hf[8];
#pragma unroll
      for (int e = 0; e < 8; ++e) hf[e] = bf2f(hv[e]);
#pragma unroll
      for (int j = 0; j < 10; ++j) {
        ushort8 wv = *(const ushort8*)(&wl[j][kc * 8]);
#pragma unroll
        for (int e = 0; e < 8; ++e) p[j] = fmaf(hf[e], bf2f(wv[e]), p[j]);
      }
    }
#pragma unroll
    for (int j = 0; j < 10; ++j)
#pragma unroll
      for (int off = 32; off > 0; off >>= 1) p[j] += __shfl_down(p[j], off);
    if (lane == 0) {
#pragma unroll
      for (int j = 0; j < 10; ++j) red[wvi][j] = p[j];
    }
    __syncthreads();
    if (t < 10) {
      float s = red[0][t] + red[1][t] + red[2][t] + red[3][t];
      s += (t < 2) ? cb[t] : bb[t - 2];
      if (t < 2) out[m * 2 + t] = s;
      else out[4000 + m * 8 + (t - 2)] = s;
    }
    __syncthreads();
  }
}

extern "C" void kernel_launch(void* const* d_in, const int* in_sizes, int n_in,
                              void* d_out, int out_size, void* d_ws, size_t ws_size,
                              hipStream_t stream) {
  const float* img    = (const float*)d_in[0];
  const int*   regions= (const int*)d_in[1];
  const float* conv_w = (const float*)d_in[2];
  const float* conv_b = (const float*)d_in[3];
  const float* fc1_w  = (const float*)d_in[4];
  const float* fc1_b  = (const float*)d_in[5];
  const float* fc2_w  = (const float*)d_in[6];
  const float* fc2_b  = (const float*)d_in[7];
  const float* cls_w  = (const float*)d_in[8];
  const float* cls_b  = (const float*)d_in[9];
  const float* bbox_w = (const float*)d_in[10];
  const float* bbox_b = (const float*)d_in[11];
  float* out = (float*)d_out;

  char* ws = (char*)d_ws;
  // layout (bytes), total 105,644,032:
  //   [0, 33554432)          M1 [512][512][64] bf16; dead after roipool2
  //                          -> h1 [0,16M), h2 [16M,32M)
  //   [33554432, 46399488)   feat [2048][3136] bf16
  //   [46399488, 72089600)   w1b  [4096][3136] bf16
  //   [72089600, 105644032)  w2b  [4096][4096] bf16
  u16* M1   = (u16*)(ws);
  u16* h1   = (u16*)(ws);
  u16* h2   = (u16*)(ws + 16777216);
  u16* feat = (u16*)(ws + 33554432);
  u16* w1b  = (u16*)(ws + 46399488);
  u16* w2b  = (u16*)(ws + 72089600);

  conv_vmax_k<<<1024, 512, 0, stream>>>(img, conv_w, conv_b, M1);
  roipool2_k<<<2048, 256, 0, stream>>>(M1, regions, feat);
  f2bf2_k<<<2048, 256, 0, stream>>>(fc1_w, w1b, 3211264, fc2_w, w2b, 7405568);
  gemm8_bt_relu_k<<<256, 512, 0, stream>>>(feat, w1b, fc1_b, h1, 4096, 3136);
  gemm8_bt_relu_k<<<256, 512, 0, stream>>>(h1, w2b, fc2_b, h2, 4096, 4096);
  heads_k<<<250, 256, 0, stream>>>(h2, cls_w, cls_b, bbox_w, bbox_b, out);
}